// Round 5
// baseline (117.358 us; speedup 1.0000x reference)
//
#include <hip/hip_runtime.h>
#include <hip/hip_bf16.h>
#include <cmath>

#define N_J   44      // 4 delta + 8 theta + 32 gamma
#define KDIM  128
#define NCLS  5
#define NT    3       // n-tiles of 16 (44 padded to 48)
#define WCE_OFF (N_J * KDIM)   // ws offset of padded [48][5] classifier weights

typedef __attribute__((ext_vector_type(8))) short bf16x8;
typedef __attribute__((ext_vector_type(4))) float f32x4;
typedef __attribute__((ext_vector_type(4))) unsigned int u32x4;

union ABf { bf16x8 b; u32x4 u; };

// ---------------------------------------------------------------------------
__device__ __forceinline__ float fast_tanh(float a) {
    float z = fminf(fabsf(a), 15.0f);
    float e = __expf(2.0f * z);
    float t = fmaf(-2.0f, __builtin_amdgcn_rcpf(e + 1.0f), 1.0f);
    return copysignf(t, a);
}

// packed f32x2 -> bf16x2 (one v_cvt_pk_bf16_f32); union pun, not bit_cast
// (__hip_bfloat162 has a non-trivial ctor on this ROCm -> bit_cast rejected)
__device__ __forceinline__ unsigned pk_bf16(float a, float b) {
    union { __hip_bfloat162 h; unsigned u; } p;
    p.h = __float22bfloat162_rn(make_float2(a, b));
    return p.u;
}

// ---------------------------------------------------------------------------
// prep: W_all^T [44][128] f32 at ws[0..5632), Wc_eff padded [48][5] (gamma
// rows scaled by C, rows 44..47 zero) at ws[5632..5872).
__global__ void hc_prep(const float* __restrict__ Wd, const float* __restrict__ Wt,
                        const float* __restrict__ Wg, const float* __restrict__ Wc,
                        float C, float* __restrict__ ws) {
    int t = threadIdx.x;
    for (int idx = t; idx < N_J * KDIM; idx += 256) {
        int j = idx / KDIM, k = idx % KDIM;
        float v;
        if (j < 4)       v = Wd[k * 4  + j];
        else if (j < 12) v = Wt[k * 8  + (j - 4)];
        else             v = Wg[k * 32 + (j - 12)];
        ws[idx] = v;
    }
    for (int idx = t; idx < 48 * NCLS; idx += 256) {
        int j = idx / NCLS;
        float v = (j < N_J) ? Wc[idx] * (j >= 12 ? C : 1.0f) : 0.0f;
        ws[WCE_OFF + idx] = v;
    }
}

// ---------------------------------------------------------------------------
// main: 16-row tiles per wave via mfma_f32_16x16x32_bf16, bf16 A (no split),
// B frags in VGPRs, one-tile-deep software pipeline on the x loads.
__global__ __launch_bounds__(256) void hc_main(
        const float* __restrict__ x, const float* __restrict__ ws,
        const float* __restrict__ bc, float* __restrict__ out, int nrows) {
    const int lane = threadIdx.x & 63;
    const int n    = lane & 15;        // A-row-in-tile / B-col / C-col
    const int g    = lane >> 4;        // k-group (and C row-group)
    const long long wave   = ((long long)blockIdx.x * blockDim.x + threadIdx.x) >> 6;
    const long long nwaves = ((long long)gridDim.x * blockDim.x) >> 6;
    const long long ntiles = (nrows + 15) / 16;

    // ---- B fragments: 3 n-tiles x 4 k-blocks, bf16, held in VGPRs ---------
    bf16x8 Bf[NT][4];
#pragma unroll
    for (int t = 0; t < NT; ++t) {
        const int j = t * 16 + n;
        const bool jv = (j < N_J);
#pragma unroll
        for (int kb = 0; kb < 4; ++kb) {
            float4 q0 = {0,0,0,0}, q1 = {0,0,0,0};
            if (jv) {
                const float4* wp = reinterpret_cast<const float4*>(ws + j * KDIM + kb * 32 + g * 8);
                q0 = wp[0]; q1 = wp[1];
            }
            ABf bb;
            bb.u[0] = pk_bf16(q0.x, q0.y); bb.u[1] = pk_bf16(q0.z, q0.w);
            bb.u[2] = pk_bf16(q1.x, q1.y); bb.u[3] = pk_bf16(q1.z, q1.w);
            Bf[t][kb] = bb.b;
        }
    }

    // ---- classifier weights for this lane's j-columns ----------------------
    float wce[NT][NCLS];
#pragma unroll
    for (int t = 0; t < NT; ++t)
#pragma unroll
        for (int c = 0; c < NCLS; ++c)
            wce[t][c] = ws[WCE_OFF + (t * 16 + n) * NCLS + c];
    const float bcv = bc[n < NCLS ? n : 0];

    float4 raw[8];
    const float4 f4z = {0,0,0,0};

#define LOAD_RAW(T) do {                                                     \
        const long long row_ = (T) * 16 + n;                                 \
        const bool rk_ = row_ < (long long)nrows;                            \
        const float4* xp_ = reinterpret_cast<const float4*>(x)               \
                            + (unsigned)(row_ * 32 + g * 2);                 \
        _Pragma("unroll")                                                    \
        for (int kb_ = 0; kb_ < 4; ++kb_) {                                  \
            raw[2*kb_]     = rk_ ? xp_[kb_ * 8]     : f4z;                   \
            raw[2*kb_ + 1] = rk_ ? xp_[kb_ * 8 + 1] : f4z;                   \
        }                                                                    \
    } while (0)

    long long tile = wave;
    if (tile < ntiles) LOAD_RAW(tile);

    while (tile < ntiles) {
        // ---- convert this tile's A to bf16 frags (frees raw for prefetch) --
        bf16x8 ah[4];
#pragma unroll
        for (int kb = 0; kb < 4; ++kb) {
            const float4 q0 = raw[2*kb], q1 = raw[2*kb + 1];
            ABf aa;
            aa.u[0] = pk_bf16(q0.x, q0.y); aa.u[1] = pk_bf16(q0.z, q0.w);
            aa.u[2] = pk_bf16(q1.x, q1.y); aa.u[3] = pk_bf16(q1.z, q1.w);
            ah[kb] = aa.b;
        }

        // ---- prefetch next tile while MFMA + epilogue run ------------------
        const long long nextt = tile + nwaves;
        if (nextt < ntiles) LOAD_RAW(nextt);

        f32x4 acc[NT];
#pragma unroll
        for (int t = 0; t < NT; ++t) acc[t] = f32x4{0.0f, 0.0f, 0.0f, 0.0f};
#pragma unroll
        for (int kb = 0; kb < 4; ++kb)
#pragma unroll
            for (int t = 0; t < NT; ++t)
                acc[t] = __builtin_amdgcn_mfma_f32_16x16x32_bf16(ah[kb], Bf[t][kb], acc[t], 0, 0, 0);

        // ---- epilogue: tanh, per-lane classifier partials, 16-lane reduce --
        // lane holds C[row = g*4 + r][col j = t*16 + n] in acc[t][r]
        float part[4][NCLS];
#pragma unroll
        for (int r = 0; r < 4; ++r) {
            float t0 = fast_tanh(acc[0][r]);
            float t1 = fast_tanh(acc[1][r]);
            float t2 = fast_tanh(acc[2][r]);
#pragma unroll
            for (int c = 0; c < NCLS; ++c)
                part[r][c] = fmaf(t0, wce[0][c], fmaf(t1, wce[1][c], t2 * wce[2][c]));
        }
#pragma unroll
        for (int m = 1; m <= 8; m <<= 1)
#pragma unroll
            for (int r = 0; r < 4; ++r)
#pragma unroll
                for (int c = 0; c < NCLS; ++c)
                    part[r][c] += __shfl_xor(part[r][c], m, 16);

        const long long rowb = tile * 16;
#pragma unroll
        for (int r = 0; r < 4; ++r) {
            float o = part[r][0];
            o = (n == 1) ? part[r][1] : o;
            o = (n == 2) ? part[r][2] : o;
            o = (n == 3) ? part[r][3] : o;
            o = (n == 4) ? part[r][4] : o;
            const long long ro = rowb + g * 4 + r;
            if (n < NCLS && ro < (long long)nrows)
                out[ro * NCLS + n] = o + bcv;
        }
        tile = nextt;
    }
#undef LOAD_RAW
}

// ---------------------------------------------------------------------------
extern "C" void kernel_launch(void* const* d_in, const int* in_sizes, int n_in,
                              void* d_out, int out_size, void* d_ws, size_t ws_size,
                              hipStream_t stream) {
    const float* x  = (const float*)d_in[0];
    const float* Wd = (const float*)d_in[1];
    const float* Wt = (const float*)d_in[2];
    const float* Wg = (const float*)d_in[3];
    const float* Wc = (const float*)d_in[4];
    const float* bc = (const float*)d_in[5];
    float* out = (float*)d_out;
    const int nrows = in_sizes[0] / KDIM;

    // -------- host: closed-form gamma amplitude scale C (data-independent) ---
    const double dt = 0.01, twopi = 6.283185307179586476925286766559;
    double fd[4], ft[8], pht[8];
    for (int i = 0; i < 4; ++i) fd[i] = 1.0 + 3.0 * (double)i / 3.0;   // 1..4
    for (int i = 0; i < 8; ++i) { ft[i] = 4.0 + 4.0 * (double)i / 7.0; pht[i] = 0.0; }
    double Csum = 0.0;
    for (int k = 0; k < 5; ++k) {
        double s = 0.0, c = 0.0;
        for (int i = 0; i < 4; ++i) { double p = twopi * fd[i] * dt * (double)k; s += sin(p); c += cos(p); }
        double mpd = atan2(s * 0.25, c * 0.25);
        double s2 = 0.0, c2 = 0.0;
        for (int i = 0; i < 8; ++i) { s2 += sin(pht[i]); c2 += cos(pht[i]); }
        double mpt = atan2(s2 * 0.125, c2 * 0.125);
        double pac = 1.0 + 0.3 * cos(mpt);
        Csum += pac * pow(1.0 - dt, 4.0 - (double)k);
        for (int i = 0; i < 8; ++i)
            pht[i] += dt * (twopi * ft[i] + 2.0 * sin(mpd - pht[i]));
    }
    const double Cd = pow(1.0 - dt, 5.0) + dt * Csum;
    const float C = (float)Cd;

    hc_prep<<<1, 256, 0, stream>>>(Wd, Wt, Wg, Wc, C, (float*)d_ws);
    hc_main<<<2048, 256, 0, stream>>>(x, (const float*)d_ws, bc, out, nrows);
}

// Round 6
// 114.842 us; speedup vs baseline: 1.0219x; 1.0219x over previous
//
#include <hip/hip_runtime.h>
#include <hip/hip_bf16.h>
#include <cmath>

#define N_J   44      // 4 delta + 8 theta + 32 gamma
#define KDIM  128
#define NCLS  5
#define NT    3       // n-tiles of 16 (44 padded to 48)
#define WCE_OFF (N_J * KDIM)   // ws offset of padded [48][5] classifier weights

typedef __attribute__((ext_vector_type(8))) short bf16x8;
typedef __attribute__((ext_vector_type(4))) float f32x4;
typedef __attribute__((ext_vector_type(4))) unsigned int u32x4;

union ABf { bf16x8 b; u32x4 u; };

// ---------------------------------------------------------------------------
__device__ __forceinline__ float fast_tanh(float a) {
    float z = fminf(fabsf(a), 15.0f);
    float e = __expf(2.0f * z);
    float t = fmaf(-2.0f, __builtin_amdgcn_rcpf(e + 1.0f), 1.0f);
    return copysignf(t, a);
}

// packed f32x2 -> bf16x2 (one v_cvt_pk_bf16_f32); union pun (bit_cast rejects
// __hip_bfloat162's non-trivial ctor on this ROCm)
__device__ __forceinline__ unsigned pk_bf16(float a, float b) {
    union { __hip_bfloat162 h; unsigned u; } p;
    p.h = __float22bfloat162_rn(make_float2(a, b));
    return p.u;
}

// ---------------------------------------------------------------------------
// prep: W_all^T [44][128] f32 at ws[0..5632), Wc_eff padded [48][5] (gamma
// rows scaled by C, rows 44..47 zero) at ws[5632..5872).
__global__ void hc_prep(const float* __restrict__ Wd, const float* __restrict__ Wt,
                        const float* __restrict__ Wg, const float* __restrict__ Wc,
                        float C, float* __restrict__ ws) {
    int t = threadIdx.x;
    for (int idx = t; idx < N_J * KDIM; idx += 256) {
        int j = idx / KDIM, k = idx % KDIM;
        float v;
        if (j < 4)       v = Wd[k * 4  + j];
        else if (j < 12) v = Wt[k * 8  + (j - 4)];
        else             v = Wg[k * 32 + (j - 12)];
        ws[idx] = v;
    }
    for (int idx = t; idx < 48 * NCLS; idx += 256) {
        int j = idx / NCLS;
        float v = (j < N_J) ? Wc[idx] * (j >= 12 ? C : 1.0f) : 0.0f;
        ws[WCE_OFF + idx] = v;
    }
}

// ---------------------------------------------------------------------------
// main: 16-row tiles per wave via mfma_f32_16x16x32_bf16 (bf16 A, no split),
// B frags in VGPRs. R3's proven loop structure: loads at top of iteration,
// raw short-lived, per-kb convert right before its MFMAs (counted vmcnt).
__global__ __launch_bounds__(256) void hc_main(
        const float* __restrict__ x, const float* __restrict__ ws,
        const float* __restrict__ bc, float* __restrict__ out, int nrows) {
    const int lane = threadIdx.x & 63;
    const int n    = lane & 15;        // A-row-in-tile / B-col / C-col
    const int g    = lane >> 4;        // k-group (and C row-group)
    const long long wave   = ((long long)blockIdx.x * blockDim.x + threadIdx.x) >> 6;
    const long long nwaves = ((long long)gridDim.x * blockDim.x) >> 6;
    const long long ntiles = (nrows + 15) / 16;

    // ---- B fragments: 3 n-tiles x 4 k-blocks, bf16, held in VGPRs ---------
    bf16x8 Bf[NT][4];
#pragma unroll
    for (int t = 0; t < NT; ++t) {
        const int j = t * 16 + n;
        const bool jv = (j < N_J);
#pragma unroll
        for (int kb = 0; kb < 4; ++kb) {
            float4 q0 = {0,0,0,0}, q1 = {0,0,0,0};
            if (jv) {
                const float4* wp = reinterpret_cast<const float4*>(ws + j * KDIM + kb * 32 + g * 8);
                q0 = wp[0]; q1 = wp[1];
            }
            ABf bb;
            bb.u[0] = pk_bf16(q0.x, q0.y); bb.u[1] = pk_bf16(q0.z, q0.w);
            bb.u[2] = pk_bf16(q1.x, q1.y); bb.u[3] = pk_bf16(q1.z, q1.w);
            Bf[t][kb] = bb.b;
        }
    }

    // ---- classifier weights for this lane's j-columns ----------------------
    float wce[NT][NCLS];
#pragma unroll
    for (int t = 0; t < NT; ++t)
#pragma unroll
        for (int c = 0; c < NCLS; ++c)
            wce[t][c] = ws[WCE_OFF + (t * 16 + n) * NCLS + c];
    const float bcv = bc[n < NCLS ? n : 0];

    for (long long tile = wave; tile < ntiles; tile += nwaves) {
        const long long rowb = tile * 16;
        const long long row  = rowb + n;
        const bool rok = (row < (long long)nrows);

        // ---- load A: this lane's 32 floats (row `row`, k = kb*32 + g*8 ..+8)
        float4 raw[8];
        const float4* xp = reinterpret_cast<const float4*>(x) + row * 32 + g * 2;
#pragma unroll
        for (int kb = 0; kb < 4; ++kb) {
            raw[2*kb]     = rok ? xp[kb * 8]     : float4{0,0,0,0};
            raw[2*kb + 1] = rok ? xp[kb * 8 + 1] : float4{0,0,0,0};
        }

        f32x4 acc[NT];
#pragma unroll
        for (int t = 0; t < NT; ++t) acc[t] = f32x4{0.0f, 0.0f, 0.0f, 0.0f};

#pragma unroll
        for (int kb = 0; kb < 4; ++kb) {
            ABf aa;
            aa.u[0] = pk_bf16(raw[2*kb].x,   raw[2*kb].y);
            aa.u[1] = pk_bf16(raw[2*kb].z,   raw[2*kb].w);
            aa.u[2] = pk_bf16(raw[2*kb+1].x, raw[2*kb+1].y);
            aa.u[3] = pk_bf16(raw[2*kb+1].z, raw[2*kb+1].w);
#pragma unroll
            for (int t = 0; t < NT; ++t)
                acc[t] = __builtin_amdgcn_mfma_f32_16x16x32_bf16(aa.b, Bf[t][kb], acc[t], 0, 0, 0);
        }

        // ---- epilogue: tanh, per-lane classifier partials, 16-lane reduce --
        // lane holds C[row = g*4 + r][col j = t*16 + n] in acc[t][r]
        float part[4][NCLS];
#pragma unroll
        for (int r = 0; r < 4; ++r) {
            float t0 = fast_tanh(acc[0][r]);
            float t1 = fast_tanh(acc[1][r]);
            float t2 = fast_tanh(acc[2][r]);
#pragma unroll
            for (int c = 0; c < NCLS; ++c)
                part[r][c] = fmaf(t0, wce[0][c], fmaf(t1, wce[1][c], t2 * wce[2][c]));
        }
#pragma unroll
        for (int m = 1; m <= 8; m <<= 1)
#pragma unroll
            for (int r = 0; r < 4; ++r)
#pragma unroll
                for (int c = 0; c < NCLS; ++c)
                    part[r][c] += __shfl_xor(part[r][c], m, 16);

        // lanes with n < 5 write class n of rows rowb + g*4 + r  (80B/group)
#pragma unroll
        for (int r = 0; r < 4; ++r) {
            float o = part[r][0];
            o = (n == 1) ? part[r][1] : o;
            o = (n == 2) ? part[r][2] : o;
            o = (n == 3) ? part[r][3] : o;
            o = (n == 4) ? part[r][4] : o;
            const long long ro = rowb + g * 4 + r;
            if (n < NCLS && ro < (long long)nrows)
                out[ro * NCLS + n] = o + bcv;
        }
    }
}

// ---------------------------------------------------------------------------
extern "C" void kernel_launch(void* const* d_in, const int* in_sizes, int n_in,
                              void* d_out, int out_size, void* d_ws, size_t ws_size,
                              hipStream_t stream) {
    const float* x  = (const float*)d_in[0];
    const float* Wd = (const float*)d_in[1];
    const float* Wt = (const float*)d_in[2];
    const float* Wg = (const float*)d_in[3];
    const float* Wc = (const float*)d_in[4];
    const float* bc = (const float*)d_in[5];
    float* out = (float*)d_out;
    const int nrows = in_sizes[0] / KDIM;

    // -------- host: closed-form gamma amplitude scale C (data-independent) ---
    const double dt = 0.01, twopi = 6.283185307179586476925286766559;
    double fd[4], ft[8], pht[8];
    for (int i = 0; i < 4; ++i) fd[i] = 1.0 + 3.0 * (double)i / 3.0;   // 1..4
    for (int i = 0; i < 8; ++i) { ft[i] = 4.0 + 4.0 * (double)i / 7.0; pht[i] = 0.0; }
    double Csum = 0.0;
    for (int k = 0; k < 5; ++k) {
        double s = 0.0, c = 0.0;
        for (int i = 0; i < 4; ++i) { double p = twopi * fd[i] * dt * (double)k; s += sin(p); c += cos(p); }
        double mpd = atan2(s * 0.25, c * 0.25);
        double s2 = 0.0, c2 = 0.0;
        for (int i = 0; i < 8; ++i) { s2 += sin(pht[i]); c2 += cos(pht[i]); }
        double mpt = atan2(s2 * 0.125, c2 * 0.125);
        double pac = 1.0 + 0.3 * cos(mpt);
        Csum += pac * pow(1.0 - dt, 4.0 - (double)k);
        for (int i = 0; i < 8; ++i)
            pht[i] += dt * (twopi * ft[i] + 2.0 * sin(mpd - pht[i]));
    }
    const double Cd = pow(1.0 - dt, 5.0) + dt * Csum;
    const float C = (float)Cd;

    hc_prep<<<1, 256, 0, stream>>>(Wd, Wt, Wg, Wc, C, (float*)d_ws);
    hc_main<<<2048, 256, 0, stream>>>(x, (const float*)d_ws, bc, out, nrows);
}

// Round 7
// 73.859 us; speedup vs baseline: 1.5890x; 1.5549x over previous
//
#include <hip/hip_runtime.h>
#include <cmath>

#define N_J   44      // 4 delta + 8 theta + 32 gamma
#define KDIM  128
#define NCLS  5
#define NT    3       // n-tiles of 16 (44 padded to 48)
#define WCE_OFF (N_J * KDIM)   // ws offset of padded [48][5] classifier weights

typedef __attribute__((ext_vector_type(8))) short bf16x8;
typedef __attribute__((ext_vector_type(4))) float f32x4;

// ---------------------------------------------------------------------------
__device__ __forceinline__ float fast_tanh(float a) {
    float z = fminf(fabsf(a), 15.0f);
    float e = __expf(2.0f * z);
    float t = 1.0f - 2.0f / (e + 1.0f);
    return copysignf(t, a);
}

// round-to-nearest-even f32 -> bf16 bits (proven in the 93.5us kernel)
__device__ __forceinline__ short bf16_rne(float f) {
    unsigned u = __builtin_bit_cast(unsigned, f);
    unsigned r = (u + 0x7fffu + ((u >> 16) & 1u)) >> 16;
    return (short)r;
}

// ---------------------------------------------------------------------------
// prep: W_all^T [44][128] f32 at ws[0..5632), Wc_eff padded [48][5] (gamma
// rows scaled by C, rows 44..47 zero) at ws[5632..5872).
__global__ void hc_prep(const float* __restrict__ Wd, const float* __restrict__ Wt,
                        const float* __restrict__ Wg, const float* __restrict__ Wc,
                        float C, float* __restrict__ ws) {
    int t = threadIdx.x;
    for (int idx = t; idx < N_J * KDIM; idx += 256) {
        int j = idx / KDIM, k = idx % KDIM;
        float v;
        if (j < 4)       v = Wd[k * 4  + j];
        else if (j < 12) v = Wt[k * 8  + (j - 4)];
        else             v = Wg[k * 32 + (j - 12)];
        ws[idx] = v;
    }
    for (int idx = t; idx < 48 * NCLS; idx += 256) {
        int j = idx / NCLS;
        float v = (j < N_J) ? Wc[idx] * (j >= 12 ? C : 1.0f) : 0.0f;
        ws[WCE_OFF + idx] = v;
    }
}

// ---------------------------------------------------------------------------
// main: 16-row tiles per wave. SWAPPED operands: mfma(A=W^T frag, B=x frag)
// -> acc holds S^T: lane (g,n) has S[row=n][j=16t+4g+r] in acc[t][r].
// Classifier contraction is lane-local (60 fma) + 2 shuffles/class (10 total,
// was 80) + 5 contiguous stores from lanes g==0.
__global__ __launch_bounds__(256, 3) void hc_main(
        const float* __restrict__ x, const float* __restrict__ ws,
        const float* __restrict__ bc, float* __restrict__ out, int nrows) {
    const int lane = threadIdx.x & 63;
    const int n    = lane & 15;        // x-row-in-tile (B-col / C-col)
    const int g    = lane >> 4;        // k-group (and C row-group)
    const long long wave   = ((long long)blockIdx.x * blockDim.x + threadIdx.x) >> 6;
    const long long nwaves = ((long long)gridDim.x * blockDim.x) >> 6;
    const long long ntiles = (nrows + 15) / 16;

    // ---- W^T fragments (A-operand): lane holds W^T[j = t*16 + n][k-chunk g]
    // (identical per-lane data to the old B-frag -> same loads as the 93.5us
    // kernel, just passed as the FIRST mfma operand now)
    bf16x8 Bf[NT][4];
#pragma unroll
    for (int t = 0; t < NT; ++t) {
        const int j = t * 16 + n;
        const bool jv = (j < N_J);
#pragma unroll
        for (int kb = 0; kb < 4; ++kb) {
            float4 q0 = {0,0,0,0}, q1 = {0,0,0,0};
            if (jv) {
                const float4* wp = reinterpret_cast<const float4*>(ws + j * KDIM + kb * 32 + g * 8);
                q0 = wp[0]; q1 = wp[1];
            }
            bf16x8 bb;
            bb[0] = bf16_rne(q0.x); bb[1] = bf16_rne(q0.y);
            bb[2] = bf16_rne(q0.z); bb[3] = bf16_rne(q0.w);
            bb[4] = bf16_rne(q1.x); bb[5] = bf16_rne(q1.y);
            bb[6] = bf16_rne(q1.z); bb[7] = bf16_rne(q1.w);
            Bf[t][kb] = bb;
        }
    }

    // ---- classifier weights for THIS lane's 12 j-values (j = 16t + 4g + r)
    float wceR[NT][4][NCLS];
#pragma unroll
    for (int t = 0; t < NT; ++t)
#pragma unroll
        for (int r = 0; r < 4; ++r) {
            const int j = t * 16 + g * 4 + r;
#pragma unroll
            for (int c = 0; c < NCLS; ++c)
                wceR[t][r][c] = ws[WCE_OFF + j * NCLS + c];
        }
    float bcv[NCLS];
#pragma unroll
    for (int c = 0; c < NCLS; ++c) bcv[c] = bc[c];

    for (long long tile = wave; tile < ntiles; tile += nwaves) {
        const long long rowb = tile * 16;
        const long long row  = rowb + n;
        const bool rok = (row < (long long)nrows);

        // ---- load x: this lane's 32 floats (row `row`, k = kb*32 + g*8 ..+8)
        float4 raw[8];
        const float4* xp = reinterpret_cast<const float4*>(x) + row * 32 + g * 2;
#pragma unroll
        for (int kb = 0; kb < 4; ++kb) {
            raw[2*kb]     = rok ? xp[kb * 8]     : float4{0,0,0,0};
            raw[2*kb + 1] = rok ? xp[kb * 8 + 1] : float4{0,0,0,0};
        }

        f32x4 acc[NT];
#pragma unroll
        for (int t = 0; t < NT; ++t) acc[t] = f32x4{0.0f, 0.0f, 0.0f, 0.0f};

#pragma unroll
        for (int kb = 0; kb < 4; ++kb) {
            float f[8] = { raw[2*kb].x, raw[2*kb].y, raw[2*kb].z, raw[2*kb].w,
                           raw[2*kb+1].x, raw[2*kb+1].y, raw[2*kb+1].z, raw[2*kb+1].w };
            bf16x8 av;
#pragma unroll
            for (int i = 0; i < 8; ++i) av[i] = bf16_rne(f[i]);
#pragma unroll
            for (int t = 0; t < NT; ++t)
                acc[t] = __builtin_amdgcn_mfma_f32_16x16x32_bf16(Bf[t][kb], av, acc[t], 0, 0, 0);
        }

        // ---- epilogue: lane-local tanh + classifier, then 2-step reduce ----
        float o[NCLS];
#pragma unroll
        for (int c = 0; c < NCLS; ++c) o[c] = 0.0f;
#pragma unroll
        for (int t = 0; t < NT; ++t)
#pragma unroll
            for (int r = 0; r < 4; ++r) {
                const float th = fast_tanh(acc[t][r]);
#pragma unroll
                for (int c = 0; c < NCLS; ++c)
                    o[c] = fmaf(th, wceR[t][r][c], o[c]);
            }
#pragma unroll
        for (int c = 0; c < NCLS; ++c) {
            o[c] += __shfl_xor(o[c], 16);
            o[c] += __shfl_xor(o[c], 32);
        }

        if (g == 0 && rok) {
#pragma unroll
            for (int c = 0; c < NCLS; ++c)
                out[row * NCLS + c] = o[c] + bcv[c];
        }
    }
}

// ---------------------------------------------------------------------------
extern "C" void kernel_launch(void* const* d_in, const int* in_sizes, int n_in,
                              void* d_out, int out_size, void* d_ws, size_t ws_size,
                              hipStream_t stream) {
    const float* x  = (const float*)d_in[0];
    const float* Wd = (const float*)d_in[1];
    const float* Wt = (const float*)d_in[2];
    const float* Wg = (const float*)d_in[3];
    const float* Wc = (const float*)d_in[4];
    const float* bc = (const float*)d_in[5];
    float* out = (float*)d_out;
    const int nrows = in_sizes[0] / KDIM;

    // -------- host: closed-form gamma amplitude scale C (data-independent) ---
    const double dt = 0.01, twopi = 6.283185307179586476925286766559;
    double fd[4], ft[8], pht[8];
    for (int i = 0; i < 4; ++i) fd[i] = 1.0 + 3.0 * (double)i / 3.0;   // 1..4
    for (int i = 0; i < 8; ++i) { ft[i] = 4.0 + 4.0 * (double)i / 7.0; pht[i] = 0.0; }
    double Csum = 0.0;
    for (int k = 0; k < 5; ++k) {
        double s = 0.0, c = 0.0;
        for (int i = 0; i < 4; ++i) { double p = twopi * fd[i] * dt * (double)k; s += sin(p); c += cos(p); }
        double mpd = atan2(s * 0.25, c * 0.25);
        double s2 = 0.0, c2 = 0.0;
        for (int i = 0; i < 8; ++i) { s2 += sin(pht[i]); c2 += cos(pht[i]); }
        double mpt = atan2(s2 * 0.125, c2 * 0.125);
        double pac = 1.0 + 0.3 * cos(mpt);
        Csum += pac * pow(1.0 - dt, 4.0 - (double)k);
        for (int i = 0; i < 8; ++i)
            pht[i] += dt * (twopi * ft[i] + 2.0 * sin(mpd - pht[i]));
    }
    const double Cd = pow(1.0 - dt, 5.0) + dt * Csum;
    const float C = (float)Cd;

    hc_prep<<<1, 256, 0, stream>>>(Wd, Wt, Wg, Wc, C, (float*)d_ws);
    hc_main<<<2048, 256, 0, stream>>>(x, (const float*)d_ws, bc, out, nrows);
}